// Round 3
// baseline (1455.370 us; speedup 1.0000x reference)
//
#include <hip/hip_runtime.h>
#include <math.h>

#define NB 96
#define NA 48
#define NF 128
#define NK 64
#define NL 6
#define NN (NB*NA)     // 4608 nodes
#define F3 (3*NF)      // 384
#define CUTF 5.0f
#define GAMMA_F ((float)(1.0 / (0.006103515625 + 1e-9)))
#define PI_F 3.14159265358979323846f

typedef __attribute__((ext_vector_type(8))) short short8;
typedef __attribute__((ext_vector_type(4))) float floatx4;

__device__ __forceinline__ float silu_f(float x) { return x / (1.0f + expf(-x)); }

__device__ __forceinline__ short f2bf(float x) {
    unsigned u = __builtin_bit_cast(unsigned, x);
    unsigned r = (u + 0x7fffu + ((u >> 16) & 1u)) >> 16;   // RNE
    return (short)r;
}

// ---------------- generic transpose+cast: src[K][N] fp32 -> dst[N][K] bf16 ----------------
// grid = N, block = K
__global__ void transpose_cast_kernel(const float* __restrict__ src, short* __restrict__ dst) {
    int n = blockIdx.x, N = gridDim.x;
    int k = threadIdx.x, K = blockDim.x;
    dst[(size_t)n*K + k] = f2bf(src[(size_t)k*N + n]);
}

// ---------------- geometry (layer-invariant): tk bf16 [i][48][64], we [i][48], dir [c][i][48] ----------------
__global__ void __launch_bounds__(384) geom_kernel(const float* __restrict__ pos,
                                                   short* __restrict__ tkG,
                                                   float* __restrict__ weG,
                                                   float* __restrict__ dirG) {
    int i = blockIdx.x;
    int b = i / NA, il = i % NA;
    int t = threadIdx.x;
    __shared__ float px[NA], py[NA], pz[NA];
    if (t < NA) {
        px[t] = pos[(b*NA+t)*3 + 0];
        py[t] = pos[(b*NA+t)*3 + 1];
        pz[t] = pos[(b*NA+t)*3 + 2];
    }
    __syncthreads();
    int j = t >> 3;            // 48 neighbors, 8 threads each
    int klo = (t & 7) * 8;
    float dx = px[il] - px[j], dy = py[il] - py[j], dz = pz[il] - pz[j];
    float d2 = dx*dx + dy*dy + dz*dz;
    float dd = sqrtf((j == il) ? 1.0f : d2);     // matches where(eye,1,d2)
    bool valid = (j != il) && (dd < CUTF);
    float we = valid ? 0.5f*(cosf(PI_F * dd / CUTF) + 1.0f) : 0.0f;
    if ((t & 7) == 0) {
        weG[(size_t)i*NA + j] = we;
        float inv = 1.0f / dd;
        dirG[0*(size_t)NN*NA + i*NA + j] = dx*inv;
        dirG[1*(size_t)NN*NA + i*NA + j] = dy*inv;
        dirG[2*(size_t)NN*NA + i*NA + j] = dz*inv;
    }
    short8 h8;
    #pragma unroll
    for (int kk = 0; kk < 8; ++kk) {
        int k = klo + kk;
        float c = CUTF * (float)k / 63.0f;
        float df = dd - c;
        h8[kk] = f2bf(expf(-GAMMA_F * df * df) * we);
    }
    *(short8*)(tkG + (size_t)i*(NA*NK) + j*NK + klo) = h8;
}

// ---------------- init: s = emb[node_atom], v = 0 ----------------
__global__ void init_kernel(const float* __restrict__ emb, const int* __restrict__ node_atom,
                            float* __restrict__ s, float* __restrict__ v) {
    int n = blockIdx.x, f = threadIdx.x;
    int a = node_atom[n];
    s[n*NF + f] = emb[a*NF + f];
    v[n*F3 + f] = 0.f;
    v[n*F3 + NF + f] = 0.f;
    v[n*F3 + 2*NF + f] = 0.f;
}

__global__ void zero_vT_kernel(float* __restrict__ vT) {
    vT[(size_t)blockIdx.x * blockDim.x + threadIdx.x] = 0.f;
}

// ---------------- phi MLP via MFMA: phi_T[t][node] = (silu(s@w1+b1)@w2+b2)^T ----------------
// block = 16 nodes, 128 threads (2 waves). Weights pre-transposed bf16 [n][k].
__global__ void __launch_bounds__(128) phi_kernel(const float* __restrict__ sIn,
                                                  const short* __restrict__ w1T,
                                                  const float* __restrict__ b1,
                                                  const short* __restrict__ w2T,
                                                  const float* __restrict__ b2,
                                                  float* __restrict__ phiT) {
    __shared__ short sA[16][NF];
    __shared__ short hA[16][NF];
    int t = threadIdx.x;
    int w = t >> 6, lane = t & 63, quad = lane >> 4, col = lane & 15;
    int n0 = blockIdx.x * 16;
    {   // stage s -> bf16 LDS
        int n = t >> 3, c0 = (t & 7) * 16;
        const float* sp = sIn + (size_t)(n0+n)*NF + c0;
        short8 ha, hb;
        #pragma unroll
        for (int jj = 0; jj < 8; ++jj) { ha[jj] = f2bf(sp[jj]); hb[jj] = f2bf(sp[8+jj]); }
        *(short8*)&sA[n][c0] = ha;
        *(short8*)&sA[n][c0+8] = hb;
    }
    __syncthreads();
    // GEMM1 (N=128) + bias + silu -> hA
    #pragma unroll
    for (int nt = 0; nt < 4; ++nt) {
        int n = (w*4 + nt)*16 + col;
        floatx4 acc = (floatx4){0.f,0.f,0.f,0.f};
        #pragma unroll
        for (int ki = 0; ki < 4; ++ki) {
            short8 a = *(const short8*)&sA[col][ki*32 + quad*8];
            short8 bb = *(const short8*)(w1T + (size_t)n*NF + ki*32 + quad*8);
            acc = __builtin_amdgcn_mfma_f32_16x16x32_bf16(a, bb, acc, 0, 0, 0);
        }
        float bias = b1[n];
        #pragma unroll
        for (int r = 0; r < 4; ++r) hA[quad*4+r][n] = f2bf(silu_f(acc[r] + bias));
    }
    __syncthreads();
    // GEMM2 (N=384) + bias -> phiT (transposed store: float4 over nodes)
    #pragma unroll
    for (int nt = 0; nt < 12; ++nt) {
        int tt = (w*12 + nt)*16 + col;
        floatx4 acc = (floatx4){0.f,0.f,0.f,0.f};
        #pragma unroll
        for (int ki = 0; ki < 4; ++ki) {
            short8 a = *(const short8*)&hA[col][ki*32 + quad*8];
            short8 bb = *(const short8*)(w2T + (size_t)tt*NF + ki*32 + quad*8);
            acc = __builtin_amdgcn_mfma_f32_16x16x32_bf16(a, bb, acc, 0, 0, 0);
        }
        float bias = b2[tt];
        floatx4 o;
        #pragma unroll
        for (int r = 0; r < 4; ++r) o[r] = acc[r] + bias;
        *(floatx4*)(phiT + (size_t)tt*NN + n0 + quad*4) = o;
    }
}

// ---------------- message: MFMA RBF projection + transposed-layout combine ----------------
// Block = target atom i, 6 waves. Wave w owns t-chunk [64w,64w+64):
//   waves 0-1 -> ds, 2-3 -> dvv, 4-5 -> dvs. Invalid pairs: tk row==0, we==0 -> contribute 0.
__global__ void __launch_bounds__(384) message_kernel(
        const float* __restrict__ sIn, const float* __restrict__ vIn,
        const float* __restrict__ phiT, const float* __restrict__ vT,
        const short* __restrict__ tkG, const short* __restrict__ rbfWT,
        const float* __restrict__ rbf_b_l,
        const float* __restrict__ weG, const float* __restrict__ dirG,
        float* __restrict__ sOut, float* __restrict__ vOut) {
    int i = blockIdx.x;
    int b = i / NA;
    int t = threadIdx.x;
    int w = t >> 6, lane = t & 63, quad = lane >> 4, col = lane & 15;
    __shared__ float red[3][NF];

    // A fragments: tk rows (j = mt*16+col), k = ks*32 + quad*8 .. +8
    short8 A[3][2];
    #pragma unroll
    for (int mt = 0; mt < 3; ++mt)
        #pragma unroll
        for (int ks = 0; ks < 2; ++ks)
            A[mt][ks] = *(const short8*)(tkG + (size_t)i*(NA*NK) + (mt*16+col)*NK + ks*32 + quad*8);
    // B fragments: rbf_w^T rows (t = w*64+nt*16+col)
    short8 Bf[4][2];
    float rb[4];
    #pragma unroll
    for (int nt = 0; nt < 4; ++nt) {
        int trow = w*64 + nt*16 + col;
        rb[nt] = rbf_b_l[trow];
        #pragma unroll
        for (int ks = 0; ks < 2; ++ks)
            Bf[nt][ks] = *(const short8*)(rbfWT + (size_t)trow*NK + ks*32 + quad*8);
    }
    // C[j,t] = tk @ rbf_w^T  (bf16 single)
    floatx4 C[3][4];
    #pragma unroll
    for (int mt = 0; mt < 3; ++mt)
        #pragma unroll
        for (int nt = 0; nt < 4; ++nt) C[mt][nt] = (floatx4){0.f,0.f,0.f,0.f};
    #pragma unroll
    for (int mt = 0; mt < 3; ++mt)
        #pragma unroll
        for (int ks = 0; ks < 2; ++ks)
            #pragma unroll
            for (int nt = 0; nt < 4; ++nt)
                C[mt][nt] = __builtin_amdgcn_mfma_f32_16x16x32_bf16(A[mt][ks], Bf[nt][ks], C[mt][nt], 0, 0, 0);

    // Combine. Lane holds (j = mt*16+quad*4+r, t = w*64+nt*16+col).
    // Transposed layouts give float4 over r for phi/v/we/dir.
    int g = w >> 1;
    int jbase = b*NA;                 // node base of this graph
    float a0[4] = {0,0,0,0}, a1[4] = {0,0,0,0}, a2[4] = {0,0,0,0};
    if (g == 0) {
        float acc[4] = {0,0,0,0};
        #pragma unroll
        for (int mt = 0; mt < 3; ++mt) {
            floatx4 we4 = *(const floatx4*)(weG + (size_t)i*NA + mt*16 + quad*4);
            #pragma unroll
            for (int nt = 0; nt < 4; ++nt) {
                int tt = w*64 + nt*16 + col;
                floatx4 ph = *(const floatx4*)(phiT + (size_t)tt*NN + jbase + mt*16 + quad*4);
                #pragma unroll
                for (int r = 0; r < 4; ++r) {
                    float Wf = fmaf(rb[nt], we4[r], C[mt][nt][r]);
                    acc[nt] = fmaf(ph[r], Wf, acc[nt]);
                }
            }
        }
        #pragma unroll
        for (int nt = 0; nt < 4; ++nt) {
            acc[nt] += __shfl_xor(acc[nt], 16, 64);
            acc[nt] += __shfl_xor(acc[nt], 32, 64);
        }
        if (quad == 0) {
            #pragma unroll
            for (int nt = 0; nt < 4; ++nt) {
                int tg = w*64 + nt*16 + col;
                sOut[(size_t)i*NF + tg] = sIn[(size_t)i*NF + tg] + acc[nt];
            }
        }
    } else if (g == 1) {              // dvv: sum_j x * v[j,c,f]
        #pragma unroll
        for (int mt = 0; mt < 3; ++mt) {
            floatx4 we4 = *(const floatx4*)(weG + (size_t)i*NA + mt*16 + quad*4);
            #pragma unroll
            for (int nt = 0; nt < 4; ++nt) {
                int tt = w*64 + nt*16 + col;         // in [128,256)
                int f  = tt - NF;
                floatx4 ph = *(const floatx4*)(phiT + (size_t)tt*NN + jbase + mt*16 + quad*4);
                floatx4 v0 = *(const floatx4*)(vT + (size_t)(0*NF + f)*NN + jbase + mt*16 + quad*4);
                floatx4 v1 = *(const floatx4*)(vT + (size_t)(1*NF + f)*NN + jbase + mt*16 + quad*4);
                floatx4 v2 = *(const floatx4*)(vT + (size_t)(2*NF + f)*NN + jbase + mt*16 + quad*4);
                #pragma unroll
                for (int r = 0; r < 4; ++r) {
                    float Wf = fmaf(rb[nt], we4[r], C[mt][nt][r]);
                    float x = ph[r] * Wf;
                    a0[nt] = fmaf(x, v0[r], a0[nt]);
                    a1[nt] = fmaf(x, v1[r], a1[nt]);
                    a2[nt] = fmaf(x, v2[r], a2[nt]);
                }
            }
        }
        #pragma unroll
        for (int nt = 0; nt < 4; ++nt) {
            a0[nt] += __shfl_xor(a0[nt], 16, 64); a0[nt] += __shfl_xor(a0[nt], 32, 64);
            a1[nt] += __shfl_xor(a1[nt], 16, 64); a1[nt] += __shfl_xor(a1[nt], 32, 64);
            a2[nt] += __shfl_xor(a2[nt], 16, 64); a2[nt] += __shfl_xor(a2[nt], 32, 64);
        }
    } else {                          // dvs: sum_j x * dir[i,j,c]
        #pragma unroll
        for (int mt = 0; mt < 3; ++mt) {
            floatx4 we4 = *(const floatx4*)(weG + (size_t)i*NA + mt*16 + quad*4);
            floatx4 d0 = *(const floatx4*)(dirG + 0*(size_t)NN*NA + (size_t)i*NA + mt*16 + quad*4);
            floatx4 d1 = *(const floatx4*)(dirG + 1*(size_t)NN*NA + (size_t)i*NA + mt*16 + quad*4);
            floatx4 d2 = *(const floatx4*)(dirG + 2*(size_t)NN*NA + (size_t)i*NA + mt*16 + quad*4);
            #pragma unroll
            for (int nt = 0; nt < 4; ++nt) {
                int tt = w*64 + nt*16 + col;         // in [256,384)
                floatx4 ph = *(const floatx4*)(phiT + (size_t)tt*NN + jbase + mt*16 + quad*4);
                #pragma unroll
                for (int r = 0; r < 4; ++r) {
                    float Wf = fmaf(rb[nt], we4[r], C[mt][nt][r]);
                    float x = ph[r] * Wf;
                    a0[nt] = fmaf(x, d0[r], a0[nt]);
                    a1[nt] = fmaf(x, d1[r], a1[nt]);
                    a2[nt] = fmaf(x, d2[r], a2[nt]);
                }
            }
        }
        #pragma unroll
        for (int nt = 0; nt < 4; ++nt) {
            a0[nt] += __shfl_xor(a0[nt], 16, 64); a0[nt] += __shfl_xor(a0[nt], 32, 64);
            a1[nt] += __shfl_xor(a1[nt], 16, 64); a1[nt] += __shfl_xor(a1[nt], 32, 64);
            a2[nt] += __shfl_xor(a2[nt], 16, 64); a2[nt] += __shfl_xor(a2[nt], 32, 64);
        }
        if (quad == 0) {
            #pragma unroll
            for (int nt = 0; nt < 4; ++nt) {
                int f = (w-4)*64 + nt*16 + col;
                red[0][f] = a0[nt]; red[1][f] = a1[nt]; red[2][f] = a2[nt];
            }
        }
    }
    __syncthreads();
    if (g == 1 && quad == 0) {
        #pragma unroll
        for (int nt = 0; nt < 4; ++nt) {
            int f = (w-2)*64 + nt*16 + col;
            vOut[(size_t)i*F3 + f]        = vIn[(size_t)i*F3 + f]        + a0[nt] + red[0][f];
            vOut[(size_t)i*F3 + NF + f]   = vIn[(size_t)i*F3 + NF + f]   + a1[nt] + red[1][f];
            vOut[(size_t)i*F3 + 2*NF + f] = vIn[(size_t)i*F3 + 2*NF + f] + a2[nt] + red[2][f];
        }
    }
}

// ---------------- update block: 4 nodes/block, in-place; also writes v_T for next layer ----------------
__global__ void update_kernel(const float* __restrict__ U, const float* __restrict__ V,
                              const float* __restrict__ w1, const float* __restrict__ b1,
                              const float* __restrict__ w2, const float* __restrict__ b2,
                              float* __restrict__ s, float* __restrict__ v,
                              float* __restrict__ vT) {
    __shared__ float st[4][NF];
    __shared__ float vt[4][3][NF];
    __shared__ float vn[4][NF];
    __shared__ float ht[4][NF];
    int f = threadIdx.x;
    int n0 = blockIdx.x * 4;
    #pragma unroll
    for (int n = 0; n < 4; ++n) {
        st[n][f]    = s[(n0+n)*NF + f];
        vt[n][0][f] = v[(n0+n)*F3 + f];
        vt[n][1][f] = v[(n0+n)*F3 + NF + f];
        vt[n][2][f] = v[(n0+n)*F3 + 2*NF + f];
    }
    __syncthreads();
    float uv[4][3] = {}, vv[4][3] = {};
    for (int g4 = 0; g4 < NF; g4 += 4) {
        float uw[4], vw[4];
        #pragma unroll
        for (int j = 0; j < 4; ++j) { uw[j] = U[(g4+j)*NF + f]; vw[j] = V[(g4+j)*NF + f]; }
        #pragma unroll
        for (int n = 0; n < 4; ++n) {
            floatx4 x0 = *(const floatx4*)&vt[n][0][g4];
            floatx4 x1 = *(const floatx4*)&vt[n][1][g4];
            floatx4 x2 = *(const floatx4*)&vt[n][2][g4];
            #pragma unroll
            for (int j = 0; j < 4; ++j) {
                uv[n][0] = fmaf(x0[j], uw[j], uv[n][0]);
                uv[n][1] = fmaf(x1[j], uw[j], uv[n][1]);
                uv[n][2] = fmaf(x2[j], uw[j], uv[n][2]);
                vv[n][0] = fmaf(x0[j], vw[j], vv[n][0]);
                vv[n][1] = fmaf(x1[j], vw[j], vv[n][1]);
                vv[n][2] = fmaf(x2[j], vw[j], vv[n][2]);
            }
        }
    }
    #pragma unroll
    for (int n = 0; n < 4; ++n)
        vn[n][f] = sqrtf(vv[n][0]*vv[n][0] + vv[n][1]*vv[n][1] + vv[n][2]*vv[n][2] + 1e-8f);
    __syncthreads();
    float bb = b1[f];
    float hacc[4] = {bb, bb, bb, bb};
    for (int g4 = 0; g4 < NF; g4 += 4) {
        float w[4], w2a[4];
        #pragma unroll
        for (int j = 0; j < 4; ++j) { w[j] = w1[(g4+j)*NF + f]; w2a[j] = w1[(NF+g4+j)*NF + f]; }
        #pragma unroll
        for (int n = 0; n < 4; ++n) {
            floatx4 sv = *(const floatx4*)&st[n][g4];
            floatx4 nv = *(const floatx4*)&vn[n][g4];
            #pragma unroll
            for (int j = 0; j < 4; ++j) {
                hacc[n] = fmaf(sv[j], w[j], hacc[n]);
                hacc[n] = fmaf(nv[j], w2a[j], hacc[n]);
            }
        }
    }
    #pragma unroll
    for (int n = 0; n < 4; ++n) ht[n][f] = silu_f(hacc[n]);
    __syncthreads();
    float b20 = b2[f], b21 = b2[NF+f], b22 = b2[2*NF+f];
    float a0[4], a1[4], a2[4];
    #pragma unroll
    for (int n = 0; n < 4; ++n) { a0[n]=b20; a1[n]=b21; a2[n]=b22; }
    for (int g4 = 0; g4 < NF; g4 += 4) {
        float w0[4], wA[4], wB[4];
        #pragma unroll
        for (int j = 0; j < 4; ++j) {
            w0[j] = w2[(g4+j)*F3 + f];
            wA[j] = w2[(g4+j)*F3 + NF + f];
            wB[j] = w2[(g4+j)*F3 + 2*NF + f];
        }
        #pragma unroll
        for (int n = 0; n < 4; ++n) {
            floatx4 hv = *(const floatx4*)&ht[n][g4];
            #pragma unroll
            for (int j = 0; j < 4; ++j) {
                a0[n] = fmaf(hv[j], w0[j], a0[n]);
                a1[n] = fmaf(hv[j], wA[j], a1[n]);
                a2[n] = fmaf(hv[j], wB[j], a2[n]);
            }
        }
    }
    float nv[4][3];
    #pragma unroll
    for (int n = 0; n < 4; ++n) {
        float dot = uv[n][0]*vv[n][0] + uv[n][1]*vv[n][1] + uv[n][2]*vv[n][2];
        s[(n0+n)*NF + f] = st[n][f] + a1[n]*dot + a2[n];
        nv[n][0] = vt[n][0][f] + a0[n]*uv[n][0];
        nv[n][1] = vt[n][1][f] + a0[n]*uv[n][1];
        nv[n][2] = vt[n][2][f] + a0[n]*uv[n][2];
        v[(n0+n)*F3 + f]        = nv[n][0];
        v[(n0+n)*F3 + NF + f]   = nv[n][1];
        v[(n0+n)*F3 + 2*NF + f] = nv[n][2];
    }
    #pragma unroll
    for (int c = 0; c < 3; ++c) {
        floatx4 o = (floatx4){nv[0][c], nv[1][c], nv[2][c], nv[3][c]};
        *(floatx4*)(vT + (size_t)(c*NF + f)*NN + n0) = o;
    }
}

// ---------------- output head ----------------
__global__ void zero_out_kernel(float* __restrict__ out) {
    out[threadIdx.x] = 0.f;
}

__global__ void out_kernel(const float* __restrict__ s,
                           const float* __restrict__ w1, const float* __restrict__ b1,
                           const float* __restrict__ w2, const float* __restrict__ b2,
                           float* __restrict__ out) {
    int n = blockIdx.x;
    int f = threadIdx.x;
    __shared__ float sh[NF];
    __shared__ float r2[2];
    sh[f] = s[n*NF + f];
    __syncthreads();
    float acc = b1[f];
    for (int g = 0; g < NF; ++g) acc = fmaf(sh[g], w1[g*NF + f], acc);
    float p = silu_f(acc) * w2[f];
    #pragma unroll
    for (int off = 32; off > 0; off >>= 1) p += __shfl_down(p, off, 64);
    if ((f & 63) == 0) r2[f >> 6] = p;
    __syncthreads();
    if (f == 0) atomicAdd(&out[n / NA], r2[0] + r2[1] + b2[0]);
}

extern "C" void kernel_launch(void* const* d_in, const int* in_sizes, int n_in,
                              void* d_out, int out_size, void* d_ws, size_t ws_size,
                              hipStream_t stream) {
    (void)in_sizes; (void)n_in; (void)out_size; (void)ws_size;
    const float* pos      = (const float*)d_in[1];
    const int*   node_atom= (const int*)  d_in[3];
    const float* emb      = (const float*)d_in[4];
    const float* msg_w1   = (const float*)d_in[5];
    const float* msg_b1   = (const float*)d_in[6];
    const float* msg_w2   = (const float*)d_in[7];
    const float* msg_b2   = (const float*)d_in[8];
    const float* rbf_w    = (const float*)d_in[9];
    const float* rbf_b    = (const float*)d_in[10];
    const float* upd_U    = (const float*)d_in[11];
    const float* upd_V    = (const float*)d_in[12];
    const float* upd_w1   = (const float*)d_in[13];
    const float* upd_b1   = (const float*)d_in[14];
    const float* upd_w2   = (const float*)d_in[15];
    const float* upd_b2   = (const float*)d_in[16];
    const float* out_w1   = (const float*)d_in[17];
    const float* out_b1   = (const float*)d_in[18];
    const float* out_w2   = (const float*)d_in[19];
    const float* out_b2   = (const float*)d_in[20];
    float* out = (float*)d_out;

    float* ws   = (float*)d_ws;
    float* sA   = ws; ws += (size_t)NN*NF;
    float* sB   = ws; ws += (size_t)NN*NF;
    float* vA   = ws; ws += (size_t)NN*F3;
    float* vB   = ws; ws += (size_t)NN*F3;
    float* phiT = ws; ws += (size_t)F3*NN;
    float* vT   = ws; ws += (size_t)F3*NN;
    float* weG  = ws; ws += (size_t)NN*NA;
    float* dirG = ws; ws += (size_t)3*NN*NA;
    short* tkG  = (short*)ws;
    short* w1T  = tkG + (size_t)NN*NA*NK;
    short* w2T  = w1T + (size_t)NL*NF*NF;
    short* rbfWT= w2T + (size_t)NL*NF*F3;

    // per-call prep (layer-invariant geometry + weight transposes)
    for (int l = 0; l < NL; ++l) {
        transpose_cast_kernel<<<NF, NF, 0, stream>>>(msg_w1 + (size_t)l*NF*NF, w1T + (size_t)l*NF*NF);
        transpose_cast_kernel<<<F3, NF, 0, stream>>>(msg_w2 + (size_t)l*NF*F3, w2T + (size_t)l*NF*F3);
        transpose_cast_kernel<<<F3, NK, 0, stream>>>(rbf_w + (size_t)l*NK*F3, rbfWT + (size_t)l*F3*NK);
    }
    geom_kernel<<<NN, 384, 0, stream>>>(pos, tkG, weG, dirG);
    init_kernel<<<NN, NF, 0, stream>>>(emb, node_atom, sA, vA);
    zero_vT_kernel<<<(F3*NN)/256, 256, 0, stream>>>(vT);

    float* sC = sA; float* vC = vA; float* sN = sB; float* vN = vB;
    for (int l = 0; l < NL; ++l) {
        phi_kernel<<<NN/16, 128, 0, stream>>>(sC, w1T + (size_t)l*NF*NF, msg_b1 + (size_t)l*NF,
                                              w2T + (size_t)l*NF*F3, msg_b2 + (size_t)l*F3, phiT);
        message_kernel<<<NN, 384, 0, stream>>>(sC, vC, phiT, vT,
                                               tkG, rbfWT + (size_t)l*F3*NK, rbf_b + (size_t)l*F3,
                                               weG, dirG, sN, vN);
        update_kernel<<<NN/4, NF, 0, stream>>>(upd_U + (size_t)l*NF*NF, upd_V + (size_t)l*NF*NF,
                                               upd_w1 + (size_t)l*2*NF*NF, upd_b1 + (size_t)l*NF,
                                               upd_w2 + (size_t)l*NF*F3, upd_b2 + (size_t)l*F3,
                                               sN, vN, vT);
        float* tp;
        tp = sC; sC = sN; sN = tp;
        tp = vC; vC = vN; vN = tp;
    }
    zero_out_kernel<<<1, NB, 0, stream>>>(out);
    out_kernel<<<NN, NF, 0, stream>>>(sC, out_w1, out_b1, out_w2, out_b2, out);
}